// Round 1
// baseline (1107.700 us; speedup 1.0000x reference)
//
#include <hip/hip_runtime.h>
#include <math.h>

#define BM 64
#define BN 64
#define BK 32
#define LDS_W (BM + 4)

// ---------------------------------------------------------------------------
// K1: q/k/v = W * x + b       per batch: [256,512] x [512,4096]
// grid: (4096/64, 12, 16)  y: 0-3 -> q, 4-7 -> k, 8-11 -> v
// ---------------------------------------------------------------------------
__global__ __launch_bounds__(256) void k1_qkv(
    const float* __restrict__ x,
    const float* __restrict__ Wq, const float* __restrict__ bq,
    const float* __restrict__ Wk, const float* __restrict__ bk,
    const float* __restrict__ Wv, const float* __restrict__ bv,
    float* __restrict__ qo, float* __restrict__ ko, float* __restrict__ vo)
{
    __shared__ float As[BK][LDS_W];
    __shared__ float Bs[BK][LDS_W];
    const int tid = threadIdx.x;
    const int tx = tid & 15, ty = tid >> 4;
    const int b  = blockIdx.z;
    const int my = blockIdx.y;
    const int sel = my >> 2;           // 0:q 1:k 2:v
    const int m0  = (my & 3) * BM;     // row within the 256-row weight
    const int n0  = blockIdx.x * BN;

    const float* W    = (sel == 0) ? Wq : (sel == 1) ? Wk : Wv;
    const float* bias = (sel == 0) ? bq : (sel == 1) ? bk : bv;
    float* outp       = (sel == 0) ? qo : (sel == 1) ? ko : vo;

    const float* xb = x + (size_t)b * 512 * 4096;

    float acc[4][4] = {};

    for (int k0 = 0; k0 < 512; k0 += BK) {
        // A tile (T layout: W[m][k], k contiguous) -> As[k][m]
        #pragma unroll
        for (int r = 0; r < 2; ++r) {
            int f  = tid + r * 256;
            int m  = f >> 3;
            int kc = (f & 7) * 4;
            float4 a4 = *(const float4*)(W + (size_t)(m0 + m) * 512 + k0 + kc);
            As[kc + 0][m] = a4.x; As[kc + 1][m] = a4.y;
            As[kc + 2][m] = a4.z; As[kc + 3][m] = a4.w;
        }
        // B tile (N layout: x[k][n], n contiguous) -> Bs[k][n]
        #pragma unroll
        for (int r = 0; r < 2; ++r) {
            int f  = tid + r * 256;
            int kk = f >> 4;
            int nc = (f & 15) * 4;
            *(float4*)(&Bs[kk][nc]) =
                *(const float4*)(xb + (size_t)(k0 + kk) * 4096 + n0 + nc);
        }
        __syncthreads();
        #pragma unroll
        for (int kk = 0; kk < BK; ++kk) {
            float a[4], bb[4];
            #pragma unroll
            for (int i = 0; i < 4; ++i) a[i]  = As[kk][ty * 4 + i];
            #pragma unroll
            for (int j = 0; j < 4; ++j) bb[j] = Bs[kk][tx * 4 + j];
            #pragma unroll
            for (int i = 0; i < 4; ++i)
                #pragma unroll
                for (int j = 0; j < 4; ++j)
                    acc[i][j] += a[i] * bb[j];
        }
        __syncthreads();
    }

    float* ob = outp + (size_t)b * 256 * 4096;
    #pragma unroll
    for (int i = 0; i < 4; ++i) {
        int m = m0 + ty * 4 + i;
        float bv_ = bias[m];
        float4 r;
        r.x = acc[i][0] + bv_; r.y = acc[i][1] + bv_;
        r.z = acc[i][2] + bv_; r.w = acc[i][3] + bv_;
        *(float4*)(ob + (size_t)m * 4096 + n0 + tx * 4) = r;
    }
}

// ---------------------------------------------------------------------------
// K2: scores_partial[split][b][c][d] = (1/64) * sum_{n in split} q[b,c,n]*k[b,d,n]
// grid: (4, 4, 64)  z = b*4 + split ; split-K over 4x1024
// ---------------------------------------------------------------------------
__global__ __launch_bounds__(256) void k2_scores(
    const float* __restrict__ q, const float* __restrict__ kmat,
    float* __restrict__ spart)
{
    __shared__ float As[BK][LDS_W];
    __shared__ float Bs[BK][LDS_W];
    const int tid = threadIdx.x;
    const int tx = tid & 15, ty = tid >> 4;
    const int bz = blockIdx.z;
    const int b = bz >> 2;
    const int split = bz & 3;
    const int m0 = blockIdx.y * BM;   // c tile
    const int n0 = blockIdx.x * BN;   // d tile

    const float* qa = q    + (size_t)b * 256 * 4096;
    const float* kb = kmat + (size_t)b * 256 * 4096;

    float acc[4][4] = {};

    const int kbeg = split * 1024;
    for (int k0 = kbeg; k0 < kbeg + 1024; k0 += BK) {
        // A (T): q[c][n]
        #pragma unroll
        for (int r = 0; r < 2; ++r) {
            int f  = tid + r * 256;
            int m  = f >> 3;
            int kc = (f & 7) * 4;
            float4 a4 = *(const float4*)(qa + (size_t)(m0 + m) * 4096 + k0 + kc);
            As[kc + 0][m] = a4.x; As[kc + 1][m] = a4.y;
            As[kc + 2][m] = a4.z; As[kc + 3][m] = a4.w;
        }
        // B (T): k[d][n] -> Bs[n][d]
        #pragma unroll
        for (int r = 0; r < 2; ++r) {
            int f  = tid + r * 256;
            int n  = f >> 3;
            int kc = (f & 7) * 4;
            float4 b4 = *(const float4*)(kb + (size_t)(n0 + n) * 4096 + k0 + kc);
            Bs[kc + 0][n] = b4.x; Bs[kc + 1][n] = b4.y;
            Bs[kc + 2][n] = b4.z; Bs[kc + 3][n] = b4.w;
        }
        __syncthreads();
        #pragma unroll
        for (int kk = 0; kk < BK; ++kk) {
            float a[4], bb[4];
            #pragma unroll
            for (int i = 0; i < 4; ++i) a[i]  = As[kk][ty * 4 + i];
            #pragma unroll
            for (int j = 0; j < 4; ++j) bb[j] = Bs[kk][tx * 4 + j];
            #pragma unroll
            for (int i = 0; i < 4; ++i)
                #pragma unroll
                for (int j = 0; j < 4; ++j)
                    acc[i][j] += a[i] * bb[j];
        }
        __syncthreads();
    }

    float* sp = spart + ((size_t)split * 16 + b) * 256 * 256;
    #pragma unroll
    for (int i = 0; i < 4; ++i) {
        int m = m0 + ty * 4 + i;
        float4 r;
        r.x = acc[i][0] * 0.015625f; r.y = acc[i][1] * 0.015625f;
        r.z = acc[i][2] * 0.015625f; r.w = acc[i][3] * 0.015625f;
        *(float4*)(sp + (size_t)m * 256 + n0 + tx * 4) = r;
    }
}

// ---------------------------------------------------------------------------
// K3: reduce 4 split partials + softmax over d. One block (256 thr) per row.
// attn aliases spart split 0 (each thread writes only its own read address).
// ---------------------------------------------------------------------------
__global__ __launch_bounds__(256) void k3_softmax(
    const float* __restrict__ sp, float* __restrict__ attn)
{
    const int row = blockIdx.x;   // b*256 + c
    const int tid = threadIdx.x;
    const size_t STRIDE = (size_t)16 * 256 * 256;
    const size_t base = (size_t)row * 256 + tid;

    float s = sp[base] + sp[base + STRIDE] + sp[base + 2 * STRIDE] + sp[base + 3 * STRIDE];

    __shared__ float red[4];
    float m = s;
    #pragma unroll
    for (int off = 32; off >= 1; off >>= 1) m = fmaxf(m, __shfl_xor(m, off));
    if ((tid & 63) == 0) red[tid >> 6] = m;
    __syncthreads();
    m = fmaxf(fmaxf(red[0], red[1]), fmaxf(red[2], red[3]));

    float e = expf(s - m);
    float t = e;
    #pragma unroll
    for (int off = 32; off >= 1; off >>= 1) t += __shfl_xor(t, off);
    __syncthreads();
    if ((tid & 63) == 0) red[tid >> 6] = t;
    __syncthreads();
    t = red[0] + red[1] + red[2] + red[3];

    attn[base] = e / t;
}

// ---------------------------------------------------------------------------
// K4: outT[b][n][c] = sum_d attn[b][c][d] * v[b][d][n]
// GEMM: M = 4096 (spatial n), N = 256 (channel c), K = 256 (d)
// grid: (4, 64, 16)
// ---------------------------------------------------------------------------
__global__ __launch_bounds__(256) void k4_outT(
    const float* __restrict__ attn, const float* __restrict__ v,
    float* __restrict__ outT)
{
    __shared__ float As[BK][LDS_W];
    __shared__ float Bs[BK][LDS_W];
    const int tid = threadIdx.x;
    const int tx = tid & 15, ty = tid >> 4;
    const int b  = blockIdx.z;
    const int m0 = blockIdx.y * BM;   // spatial tile
    const int n0 = blockIdx.x * BN;   // channel tile

    const float* va = v    + (size_t)b * 256 * 4096;
    const float* ab = attn + (size_t)b * 256 * 256;

    float acc[4][4] = {};

    for (int k0 = 0; k0 < 256; k0 += BK) {
        // A (N): v[k=d][m=n], m contiguous -> As[k][m] direct float4
        #pragma unroll
        for (int r = 0; r < 2; ++r) {
            int f  = tid + r * 256;
            int kk = f >> 4;
            int mc = (f & 15) * 4;
            *(float4*)(&As[kk][mc]) =
                *(const float4*)(va + (size_t)(k0 + kk) * 4096 + m0 + mc);
        }
        // B (T): attn[n=c][k=d], k contiguous -> Bs[k][n]
        #pragma unroll
        for (int r = 0; r < 2; ++r) {
            int f  = tid + r * 256;
            int n  = f >> 3;
            int kc = (f & 7) * 4;
            float4 b4 = *(const float4*)(ab + (size_t)(n0 + n) * 256 + k0 + kc);
            Bs[kc + 0][n] = b4.x; Bs[kc + 1][n] = b4.y;
            Bs[kc + 2][n] = b4.z; Bs[kc + 3][n] = b4.w;
        }
        __syncthreads();
        #pragma unroll
        for (int kk = 0; kk < BK; ++kk) {
            float a[4], bb[4];
            #pragma unroll
            for (int i = 0; i < 4; ++i) a[i]  = As[kk][ty * 4 + i];
            #pragma unroll
            for (int j = 0; j < 4; ++j) bb[j] = Bs[kk][tx * 4 + j];
            #pragma unroll
            for (int i = 0; i < 4; ++i)
                #pragma unroll
                for (int j = 0; j < 4; ++j)
                    acc[i][j] += a[i] * bb[j];
        }
        __syncthreads();
    }

    float* ob = outT + (size_t)b * 4096 * 256;
    #pragma unroll
    for (int i = 0; i < 4; ++i) {
        int m = m0 + ty * 4 + i;
        *(float4*)(ob + (size_t)m * 256 + n0 + tx * 4) =
            make_float4(acc[i][0], acc[i][1], acc[i][2], acc[i][3]);
    }
}

// ---------------------------------------------------------------------------
// K5: final[b][c][sh*256+slo] = sum_{c'} Wo[c][c'] * outT[b][16c'+sh][slo] + bo[c]
// grid: (4, 8, 256)  z = b*16 + sh
// ---------------------------------------------------------------------------
__global__ __launch_bounds__(256) void k5_final(
    const float* __restrict__ Wo, const float* __restrict__ bo,
    const float* __restrict__ outT, float* __restrict__ out)
{
    __shared__ float As[BK][LDS_W];
    __shared__ float Bs[BK][LDS_W];
    const int tid = threadIdx.x;
    const int tx = tid & 15, ty = tid >> 4;
    const int bz = blockIdx.z;
    const int b  = bz >> 4;
    const int sh = bz & 15;
    const int m0 = blockIdx.y * BM;   // c tile (512/64)
    const int n0 = blockIdx.x * BN;   // s_lo tile (256/64)

    const float* Bbase = outT + (size_t)b * 4096 * 256 + (size_t)sh * 256;

    float acc[4][4] = {};

    for (int k0 = 0; k0 < 256; k0 += BK) {
        // A (T): Wo[m][k], k contiguous
        #pragma unroll
        for (int r = 0; r < 2; ++r) {
            int f  = tid + r * 256;
            int m  = f >> 3;
            int kc = (f & 7) * 4;
            float4 a4 = *(const float4*)(Wo + (size_t)(m0 + m) * 256 + k0 + kc);
            As[kc + 0][m] = a4.x; As[kc + 1][m] = a4.y;
            As[kc + 2][m] = a4.z; As[kc + 3][m] = a4.w;
        }
        // B (N): B[k][n] = Bbase + k*4096 + n, n contiguous
        #pragma unroll
        for (int r = 0; r < 2; ++r) {
            int f  = tid + r * 256;
            int kk = f >> 4;
            int nc = (f & 15) * 4;
            *(float4*)(&Bs[kk][nc]) =
                *(const float4*)(Bbase + (size_t)(k0 + kk) * 4096 + n0 + nc);
        }
        __syncthreads();
        #pragma unroll
        for (int kk = 0; kk < BK; ++kk) {
            float a[4], bb[4];
            #pragma unroll
            for (int i = 0; i < 4; ++i) a[i]  = As[kk][ty * 4 + i];
            #pragma unroll
            for (int j = 0; j < 4; ++j) bb[j] = Bs[kk][tx * 4 + j];
            #pragma unroll
            for (int i = 0; i < 4; ++i)
                #pragma unroll
                for (int j = 0; j < 4; ++j)
                    acc[i][j] += a[i] * bb[j];
        }
        __syncthreads();
    }

    float* ob = out + (size_t)b * 512 * 4096 + (size_t)sh * 256;
    #pragma unroll
    for (int i = 0; i < 4; ++i) {
        int m = m0 + ty * 4 + i;
        float bo_ = bo[m];
        float4 r;
        r.x = acc[i][0] + bo_; r.y = acc[i][1] + bo_;
        r.z = acc[i][2] + bo_; r.w = acc[i][3] + bo_;
        *(float4*)(ob + (size_t)m * 4096 + n0 + tx * 4) = r;
    }
}

// ---------------------------------------------------------------------------
extern "C" void kernel_launch(void* const* d_in, const int* in_sizes, int n_in,
                              void* d_out, int out_size, void* d_ws, size_t ws_size,
                              hipStream_t stream) {
    const float* x  = (const float*)d_in[0];
    const float* Wq = (const float*)d_in[1];
    const float* bq = (const float*)d_in[2];
    const float* Wk = (const float*)d_in[3];
    const float* bk = (const float*)d_in[4];
    const float* Wv = (const float*)d_in[5];
    const float* bv = (const float*)d_in[6];
    const float* Wo = (const float*)d_in[7];
    const float* bo = (const float*)d_in[8];
    float* out = (float*)d_out;

    float* ws = (float*)d_ws;
    const size_t SZ = (size_t)16 * 256 * 4096;   // 16.78M floats per q/k/v buffer
    float* q     = ws;
    float* kmat  = ws + SZ;
    float* v     = ws + 2 * SZ;
    float* spart = ws + 3 * SZ;                  // 4 * 16*256*256 floats
    float* attn  = spart;                        // alias split-0 (safe: per-thread RAW only)
    float* outT  = q;                            // alias q (dead after K2)

    dim3 blk(256);
    k1_qkv   <<<dim3(64, 12, 16), blk, 0, stream>>>(x, Wq, bq, Wk, bk, Wv, bv, q, kmat, v);
    k2_scores<<<dim3(4, 4, 64),   blk, 0, stream>>>(q, kmat, spart);
    k3_softmax<<<dim3(4096),      blk, 0, stream>>>(spart, attn);
    k4_outT  <<<dim3(4, 64, 16),  blk, 0, stream>>>(attn, v, outT);
    k5_final <<<dim3(4, 8, 256),  blk, 0, stream>>>(Wo, bo, outT, out);
}

// Round 2
// 295.876 us; speedup vs baseline: 3.7438x; 3.7438x over previous
//
#include <hip/hip_runtime.h>
#include <math.h>

typedef unsigned short u16;
typedef __bf16 bf16x8 __attribute__((ext_vector_type(8)));
typedef float f32x4 __attribute__((ext_vector_type(4)));
typedef unsigned short u16x4 __attribute__((ext_vector_type(4)));
typedef unsigned short u16x8 __attribute__((ext_vector_type(8)));

__device__ __forceinline__ u16 f2bf(float f) {
    unsigned int u = __float_as_uint(f);
    return (u16)((u + 0x7FFF + ((u >> 16) & 1)) >> 16);
}

// ---------------------------------------------------------------------------
// Shared 128x128x(BK=64) bf16 MFMA GEMM core. 256 threads = 4 waves (2x2).
// A: [M][K] k-contig (ldA), B: [N][K] k-contig (ldB). Both staged via
// global_load_lds(16B) into LDS layout [kb=k>>3][row][8] -> every
// quarter-wave ds_read_b128 is one contiguous 256B stretch (conflict-free).
// k-permutation freedom: A and B fragments use the identical (lane,elem)->k
// map, so the MFMA dot product is exact regardless of HW internal k order.
// ---------------------------------------------------------------------------
__device__ __forceinline__ void stage128(
    const u16* __restrict__ Ag, int ldA, const u16* __restrict__ Bg, int ldB,
    int m0, int n0, int k0, u16* Asm, u16* Bsm, int w, int l)
{
    const int row = (w & 1) * 64 + l;   // 64 consecutive rows per wave
    const int kbh = w >> 1;
    #pragma unroll
    for (int r = 0; r < 4; ++r) {
        const int kb = r * 2 + kbh;     // k-slab 0..7
        const u16* sa = Ag + (size_t)(m0 + row) * ldA + k0 + kb * 8;
        const u16* sb = Bg + (size_t)(n0 + row) * ldB + k0 + kb * 8;
        __builtin_amdgcn_global_load_lds(
            (const __attribute__((address_space(1))) unsigned int*)sa,
            (__attribute__((address_space(3))) unsigned int*)(Asm + (size_t)(r * 256 + w * 64) * 8),
            16, 0, 0);
        __builtin_amdgcn_global_load_lds(
            (const __attribute__((address_space(1))) unsigned int*)sb,
            (__attribute__((address_space(3))) unsigned int*)(Bsm + (size_t)(r * 256 + w * 64) * 8),
            16, 0, 0);
    }
}

__device__ __forceinline__ void compute128(
    const u16* Asm, const u16* Bsm, int wm, int wn, int p, int g, f32x4 acc[4][4])
{
    #pragma unroll
    for (int ks = 0; ks < 2; ++ks) {
        const int kb = ks * 4 + g;
        bf16x8 af[4], bfr[4];
        #pragma unroll
        for (int i = 0; i < 4; ++i)
            af[i] = *(const bf16x8*)(Asm + (size_t)(kb * 128 + wm + i * 16 + p) * 8);
        #pragma unroll
        for (int j = 0; j < 4; ++j)
            bfr[j] = *(const bf16x8*)(Bsm + (size_t)(kb * 128 + wn + j * 16 + p) * 8);
        #pragma unroll
        for (int i = 0; i < 4; ++i)
            #pragma unroll
            for (int j = 0; j < 4; ++j)
                acc[i][j] = __builtin_amdgcn_mfma_f32_16x16x32_bf16(af[i], bfr[j], acc[i][j], 0, 0, 0);
    }
}

__device__ __forceinline__ void gemm128(
    const u16* __restrict__ Ag, int ldA, const u16* __restrict__ Bg, int ldB,
    int m0, int n0, int kbeg, int ntiles, u16* Asm, u16* Bsm, f32x4 acc[4][4])
{
    const int tid = threadIdx.x;
    const int l = tid & 63, w = tid >> 6;
    const int p = l & 15, g = l >> 4;
    const int wm = (w >> 1) * 64, wn = (w & 1) * 64;

    stage128(Ag, ldA, Bg, ldB, m0, n0, kbeg, Asm, Bsm, w, l);
    for (int t = 0; t < ntiles; ++t) {
        __syncthreads();                 // vmcnt(0) drain: staged tile visible
        compute128(Asm, Bsm, wm, wn, p, g, acc);
        __syncthreads();                 // all reads done before overwrite
        if (t + 1 < ntiles)
            stage128(Ag, ldA, Bg, ldB, m0, n0, kbeg + (t + 1) * 64, Asm, Bsm, w, l);
    }
}

// ---------------------------------------------------------------------------
// K0: xT[b][n][c] (bf16) = x[b][c][n] (f32). 64x64 LDS transpose tiles.
// ---------------------------------------------------------------------------
__global__ __launch_bounds__(256) void k0_xpose(const float* __restrict__ x, u16* __restrict__ xT)
{
    __shared__ float Tx[64 * 65];   // [n_local][c_local], pad 65
    const int tid = threadIdx.x;
    const int b = blockIdx.z, c0 = blockIdx.y * 64, n0 = blockIdx.x * 64;
    const float* xb = x + (size_t)b * 512 * 4096;
    #pragma unroll
    for (int r = 0; r < 4; ++r) {
        int crow = (tid >> 4) + r * 16;
        int ncol = (tid & 15) * 4;
        float4 v = *(const float4*)(xb + (size_t)(c0 + crow) * 4096 + n0 + ncol);
        Tx[(ncol + 0) * 65 + crow] = v.x;
        Tx[(ncol + 1) * 65 + crow] = v.y;
        Tx[(ncol + 2) * 65 + crow] = v.z;
        Tx[(ncol + 3) * 65 + crow] = v.w;
    }
    __syncthreads();
    u16* ob = xT + (size_t)b * 4096 * 512;
    #pragma unroll
    for (int cc = 0; cc < 2; ++cc) {
        int id = cc * 256 + tid;
        int nrow = id >> 3;
        int cch = (id & 7) * 8;
        u16x8 u;
        #pragma unroll
        for (int j = 0; j < 8; ++j) u[j] = f2bf(Tx[nrow * 65 + cch + j]);
        *(u16x8*)(ob + (size_t)(n0 + nrow) * 512 + c0 + cch) = u;
    }
}

// K0b: 4 weight matrices f32 -> bf16, 131072 elems each.
__global__ __launch_bounds__(256) void k0b_wconv(
    const float* __restrict__ s0, const float* __restrict__ s1,
    const float* __restrict__ s2, const float* __restrict__ s3,
    u16* __restrict__ d0, u16* __restrict__ d1, u16* __restrict__ d2, u16* __restrict__ d3)
{
    const int sel = blockIdx.y;
    const float* s = sel == 0 ? s0 : sel == 1 ? s1 : sel == 2 ? s2 : s3;
    u16* d = sel == 0 ? d0 : sel == 1 ? d1 : sel == 2 ? d2 : d3;
    int i = (blockIdx.x * 256 + threadIdx.x) * 4;
    float4 v = *(const float4*)(s + i);
    u16x4 u = {f2bf(v.x), f2bf(v.y), f2bf(v.z), f2bf(v.w)};
    *(u16x4*)(d + i) = u;
}

// ---------------------------------------------------------------------------
// K1: q/k = W*x + b stored [c][n]; v stored transposed vT[n][d].
// grid (32, 6, 16): y = sel*2 + mtile
// ---------------------------------------------------------------------------
__global__ __launch_bounds__(256) void k1_qkv(
    const u16* __restrict__ wq, const u16* __restrict__ wk, const u16* __restrict__ wv,
    const float* __restrict__ bq, const float* __restrict__ bk, const float* __restrict__ bv,
    const u16* __restrict__ xT, u16* __restrict__ q, u16* __restrict__ k, u16* __restrict__ vT)
{
    __shared__ u16 sm[16384];
    const int b = blockIdx.z;
    const int my = blockIdx.y;
    const int sel = my >> 1;
    const int m0 = (my & 1) * 128;
    const int n0 = blockIdx.x * 128;
    const u16* A = sel == 0 ? wq : sel == 1 ? wk : wv;
    const u16* B = xT + (size_t)b * 4096 * 512;

    f32x4 acc[4][4] = {};
    gemm128(A, 512, B, 512, m0, n0, 0, 8, sm, sm + 8192, acc);

    const int tid = threadIdx.x;
    const int l = tid & 63, w = tid >> 6;
    const int p = l & 15, g = l >> 4;
    const int wm = (w >> 1) * 64, wn = (w & 1) * 64;

    if (sel < 2) {
        const float* bias = sel == 0 ? bq : bk;
        u16* out = (sel == 0 ? q : k) + ((size_t)b << 20);
        #pragma unroll
        for (int mf = 0; mf < 4; ++mf)
            #pragma unroll
            for (int nf = 0; nf < 4; ++nf) {
                int n = n0 + wn + nf * 16 + p;
                #pragma unroll
                for (int r = 0; r < 4; ++r) {
                    int m = m0 + wm + mf * 16 + g * 4 + r;
                    out[(size_t)m * 4096 + n] = f2bf(acc[mf][nf][r] + bias[m]);
                }
            }
    } else {
        u16* out = vT + ((size_t)b << 20);
        #pragma unroll
        for (int mf = 0; mf < 4; ++mf)
            #pragma unroll
            for (int nf = 0; nf < 4; ++nf) {
                int d = m0 + wm + mf * 16 + g * 4;
                int nsp = n0 + wn + nf * 16 + p;
                u16x4 u = {f2bf(acc[mf][nf][0] + bv[d + 0]),
                           f2bf(acc[mf][nf][1] + bv[d + 1]),
                           f2bf(acc[mf][nf][2] + bv[d + 2]),
                           f2bf(acc[mf][nf][3] + bv[d + 3])};
                *(u16x4*)(out + (size_t)nsp * 256 + d) = u;
            }
    }
}

// ---------------------------------------------------------------------------
// K2: score partials, split-K=8. grid (2, 2, 128): z = b*8 + split
// ---------------------------------------------------------------------------
__global__ __launch_bounds__(256) void k2_scores(
    const u16* __restrict__ q, const u16* __restrict__ kmat, float* __restrict__ spart)
{
    __shared__ u16 sm[16384];
    const int bz = blockIdx.z;
    const int b = bz >> 3, split = bz & 7;
    const int m0 = blockIdx.y * 128, n0 = blockIdx.x * 128;
    const u16* A = q    + ((size_t)b << 20);
    const u16* B = kmat + ((size_t)b << 20);

    f32x4 acc[4][4] = {};
    gemm128(A, 4096, B, 4096, m0, n0, split * 512, 8, sm, sm + 8192, acc);

    const int tid = threadIdx.x;
    const int l = tid & 63, w = tid >> 6;
    const int p = l & 15, g = l >> 4;
    const int wm = (w >> 1) * 64, wn = (w & 1) * 64;
    float* sp = spart + ((size_t)split * 16 + b) * 65536;
    #pragma unroll
    for (int mf = 0; mf < 4; ++mf)
        #pragma unroll
        for (int nf = 0; nf < 4; ++nf) {
            int n = n0 + wn + nf * 16 + p;
            #pragma unroll
            for (int r = 0; r < 4; ++r) {
                int m = m0 + wm + mf * 16 + g * 4 + r;
                sp[(size_t)m * 256 + n] = acc[mf][nf][r] * 0.015625f;
            }
        }
}

// ---------------------------------------------------------------------------
// K3: reduce 8 split partials + softmax over d -> bf16 attn. 1 block/row.
// ---------------------------------------------------------------------------
__global__ __launch_bounds__(256) void k3_softmax(
    const float* __restrict__ sp, u16* __restrict__ attn)
{
    const int row = blockIdx.x;
    const int tid = threadIdx.x;
    const size_t STRIDE = (size_t)16 * 65536;
    const size_t base = (size_t)row * 256 + tid;

    float s = 0.f;
    #pragma unroll
    for (int i = 0; i < 8; ++i) s += sp[base + i * STRIDE];

    __shared__ float red[4];
    float m = s;
    #pragma unroll
    for (int off = 32; off >= 1; off >>= 1) m = fmaxf(m, __shfl_xor(m, off));
    if ((tid & 63) == 0) red[tid >> 6] = m;
    __syncthreads();
    m = fmaxf(fmaxf(red[0], red[1]), fmaxf(red[2], red[3]));

    float e = expf(s - m);
    float t = e;
    #pragma unroll
    for (int off = 32; off >= 1; off >>= 1) t += __shfl_xor(t, off);
    __syncthreads();
    if ((tid & 63) == 0) red[tid >> 6] = t;
    __syncthreads();
    t = red[0] + red[1] + red[2] + red[3];

    attn[base] = f2bf(e / t);
}

// ---------------------------------------------------------------------------
// K4: outAttn(c, nsp) = sum_d attn[c][d] * vT[nsp][d], stored to
// outT3[b][sh=nsp&15][c][nh=nsp>>4] via LDS epilogue transpose.
// grid (32, 2, 16)
// ---------------------------------------------------------------------------
__global__ __launch_bounds__(256) void k4_pv(
    const u16* __restrict__ attn, const u16* __restrict__ vT, u16* __restrict__ outT3)
{
    __shared__ u16 sm[17920];    // 35840 B: staging (32KB) then T[128][136]
    const int b = blockIdx.z;
    const int m0 = blockIdx.y * 128;   // c tile
    const int n0 = blockIdx.x * 128;   // nsp tile
    const u16* A = attn + ((size_t)b << 16);
    const u16* B = vT   + ((size_t)b << 20);

    f32x4 acc[4][4] = {};
    gemm128(A, 256, B, 256, m0, n0, 0, 4, sm, sm + 8192, acc);
    // gemm128's final barrier guards LDS reuse.

    const int tid = threadIdx.x;
    const int l = tid & 63, w = tid >> 6;
    const int p = l & 15, g = l >> 4;
    const int wm = (w >> 1) * 64, wn = (w & 1) * 64;

    #pragma unroll
    for (int mf = 0; mf < 4; ++mf)
        #pragma unroll
        for (int nf = 0; nf < 4; ++nf) {
            int nl = wn + nf * 16 + p;
            int cl = wm + mf * 16 + g * 4;
            u16x4 u = {f2bf(acc[mf][nf][0]), f2bf(acc[mf][nf][1]),
                       f2bf(acc[mf][nf][2]), f2bf(acc[mf][nf][3])};
            *(u16x4*)(sm + (size_t)nl * 136 + cl) = u;
        }
    __syncthreads();

    #pragma unroll
    for (int cc = 0; cc < 8; ++cc) {
        int id = cc * 256 + tid;         // 0..2047
        int sh = id >> 7, cl = id & 127;
        u16x8 v;
        #pragma unroll
        for (int t = 0; t < 8; ++t) v[t] = sm[(size_t)(sh + 16 * t) * 136 + cl];
        *(u16x8*)(outT3 + (((size_t)b * 16 + sh) * 256 + m0 + cl) * 256 + (n0 >> 4)) = v;
    }
}

// ---------------------------------------------------------------------------
// K5: final[b][c][sh*256+slo] = sum_k Wo[c][k] * outT3[b][sh][slo][k] + bo[c]
// grid (2, 4, 256): z = b*16 + sh
// ---------------------------------------------------------------------------
__global__ __launch_bounds__(256) void k5_final(
    const u16* __restrict__ wo, const float* __restrict__ bo,
    const u16* __restrict__ outT3, float* __restrict__ out)
{
    __shared__ u16 sm[16384];
    const int bz = blockIdx.z;
    const int b = bz >> 4, sh = bz & 15;
    const int m0 = blockIdx.y * 128;   // c tile (512)
    const int n0 = blockIdx.x * 128;   // slo tile (256)
    const u16* B = outT3 + ((size_t)bz << 16);

    f32x4 acc[4][4] = {};
    gemm128(wo, 256, B, 256, m0, n0, 0, 4, sm, sm + 8192, acc);

    const int tid = threadIdx.x;
    const int l = tid & 63, w = tid >> 6;
    const int p = l & 15, g = l >> 4;
    const int wm = (w >> 1) * 64, wn = (w & 1) * 64;
    float* ob = out + (size_t)b * 2097152 + (size_t)sh * 256;
    #pragma unroll
    for (int mf = 0; mf < 4; ++mf)
        #pragma unroll
        for (int nf = 0; nf < 4; ++nf) {
            int n = n0 + wn + nf * 16 + p;
            #pragma unroll
            for (int r = 0; r < 4; ++r) {
                int m = m0 + wm + mf * 16 + g * 4 + r;
                ob[(size_t)m * 4096 + n] = acc[mf][nf][r] + bo[m];
            }
        }
}

// ---------------------------------------------------------------------------
extern "C" void kernel_launch(void* const* d_in, const int* in_sizes, int n_in,
                              void* d_out, int out_size, void* d_ws, size_t ws_size,
                              hipStream_t stream) {
    (void)in_sizes; (void)n_in; (void)out_size; (void)ws_size;
    const float* x  = (const float*)d_in[0];
    const float* Wq = (const float*)d_in[1];
    const float* bq = (const float*)d_in[2];
    const float* Wk = (const float*)d_in[3];
    const float* bk = (const float*)d_in[4];
    const float* Wv = (const float*)d_in[5];
    const float* bv = (const float*)d_in[6];
    const float* Wo = (const float*)d_in[7];
    const float* bo = (const float*)d_in[8];
    float* out = (float*)d_out;

    char* ws = (char*)d_ws;
    // byte offsets; max live footprint 169 MB (round 0 proved >=218 MB works)
    u16* xT   = (u16*)(ws + 0);            // 67108864 B, dead after K1
    u16* q    = (u16*)(ws + 67108864);     // 33554432 B, dead after K2
    u16* k    = (u16*)(ws + 100663296);    // 33554432 B, dead after K2
    u16* vT   = (u16*)(ws + 134217728);    // 33554432 B, dead after K4
    u16* wq   = (u16*)(ws + 167772160);
    u16* wk   = (u16*)(ws + 168034304);
    u16* wv   = (u16*)(ws + 168296448);
    u16* wo   = (u16*)(ws + 168558592);
    float* spart = (float*)(ws + 0);       // aliases xT (33.5 MB f32)
    u16* attn    = (u16*)(ws + 67108864);  // aliases q (2 MB)
    u16* outT3   = (u16*)(ws + 100663296); // aliases k (33.5 MB)

    dim3 blk(256);
    k0b_wconv <<<dim3(128, 4),    blk, 0, stream>>>(Wq, Wk, Wv, Wo, wq, wk, wv, wo);
    k0_xpose  <<<dim3(64, 8, 16), blk, 0, stream>>>(x, xT);
    k1_qkv    <<<dim3(32, 6, 16), blk, 0, stream>>>(wq, wk, wv, bq, bk, bv, xT, q, k, vT);
    k2_scores <<<dim3(2, 2, 128), blk, 0, stream>>>(q, k, spart);
    k3_softmax<<<dim3(4096),      blk, 0, stream>>>(spart, attn);
    k4_pv     <<<dim3(32, 2, 16), blk, 0, stream>>>(attn, vT, outT3);
    k5_final  <<<dim3(2, 4, 256), blk, 0, stream>>>(wo, bo, outT3, out);
}

// Round 4
// 220.139 us; speedup vs baseline: 5.0318x; 1.3440x over previous
//
#include <hip/hip_runtime.h>
#include <math.h>

typedef unsigned short u16;
typedef __bf16 bf16x8 __attribute__((ext_vector_type(8)));
typedef float f32x4 __attribute__((ext_vector_type(4)));
typedef unsigned short u16x4 __attribute__((ext_vector_type(4)));
typedef unsigned short u16x8 __attribute__((ext_vector_type(8)));

__device__ __forceinline__ u16 f2bf(float f) {
    unsigned int u = __float_as_uint(f);
    return (u16)((u + 0x7FFF + ((u >> 16) & 1)) >> 16);
}

#define BAR() do { __builtin_amdgcn_sched_barrier(0); __builtin_amdgcn_s_barrier(); __builtin_amdgcn_sched_barrier(0); } while (0)

// ===========================================================================
// 256x256 8-wave deep-pipelined bf16 GEMM (T2+T3+T4+T5), 512 threads.
// A: logical row m -> global row baseA + m*rsA, k-contig (ldA).
// B: logical row n -> global row n0 + n, k-contig (ldB).
// LDS 128KB = 2 bufs x (A 32KB + B 32KB), K-tile 64.
// 16B-chunk swizzle kc^(row&7) realized via pre-swizzled GLOBAL source +
// linear LDS dest (global_load_lds), read back with same XOR (involution).
// Pipeline: stage tile t+1 during tile t (A @phase1, B @phases2,3);
// single s_waitcnt vmcnt(4) per K-tile (never 0 in main loop).
// ===========================================================================
__device__ __forceinline__ void stage_half(
    const u16* __restrict__ g, int ld, int row0, int rstride, int kt,
    u16* lds, int w, int l)
{
    #pragma unroll
    for (int qq = 0; qq < 2; ++qq) {
        const int c0 = qq * 512 + w * 64;    // wave-uniform chunk base
        const int c  = c0 + l;
        const int r  = c >> 3, kc = c & 7;
        const int kcg = kc ^ (r & 7);
        const u16* src = g + (size_t)(row0 + r * rstride) * ld + kt + kcg * 8;
        __builtin_amdgcn_global_load_lds(
            (const __attribute__((address_space(1))) unsigned int*)src,
            (__attribute__((address_space(3))) unsigned int*)(lds + (size_t)c0 * 8),
            16, 0, 0);
    }
}

#define QUAD(q_) do {                                                          \
    bf16x8 af0[2], af1[2];                                                     \
    { int row = wm + ((q_) * 2 + 0) * 16 + p;                                  \
      af0[0] = *(const bf16x8*)(bufA + row * 64 + ((0 + g) ^ (row & 7)) * 8);  \
      af0[1] = *(const bf16x8*)(bufA + row * 64 + ((4 + g) ^ (row & 7)) * 8); }\
    { int row = wm + ((q_) * 2 + 1) * 16 + p;                                  \
      af1[0] = *(const bf16x8*)(bufA + row * 64 + ((0 + g) ^ (row & 7)) * 8);  \
      af1[1] = *(const bf16x8*)(bufA + row * 64 + ((4 + g) ^ (row & 7)) * 8); }\
    __builtin_amdgcn_s_setprio(1);                                             \
    _Pragma("unroll")                                                          \
    for (int nf = 0; nf < 4; ++nf) {                                           \
        acc[(q_)*2+0][nf] = __builtin_amdgcn_mfma_f32_16x16x32_bf16(af0[0], bfr[nf][0], acc[(q_)*2+0][nf], 0, 0, 0); \
        acc[(q_)*2+0][nf] = __builtin_amdgcn_mfma_f32_16x16x32_bf16(af0[1], bfr[nf][1], acc[(q_)*2+0][nf], 0, 0, 0); \
        acc[(q_)*2+1][nf] = __builtin_amdgcn_mfma_f32_16x16x32_bf16(af1[0], bfr[nf][0], acc[(q_)*2+1][nf], 0, 0, 0); \
        acc[(q_)*2+1][nf] = __builtin_amdgcn_mfma_f32_16x16x32_bf16(af1[1], bfr[nf][1], acc[(q_)*2+1][nf], 0, 0, 0); \
    }                                                                          \
    __builtin_amdgcn_s_setprio(0);                                             \
} while (0)

template<int NT>
__device__ __forceinline__ void gemm256(
    const u16* __restrict__ Ag, int ldA, int baseA, int rsA,
    const u16* __restrict__ Bg, int ldB, int n0,
    u16* sm, f32x4 (&acc)[8][4])
{
    const int tid = threadIdx.x;
    const int l = tid & 63, w = tid >> 6;
    const int p = l & 15, g = l >> 4;
    const int wm = (w >> 2) * 128;   // 2 M-waves
    const int wn = (w & 3) * 64;     // 4 N-waves

    // prologue: stage tile 0 (8 loads outstanding)
    stage_half(Ag, ldA, baseA,             rsA, 0, sm,         w, l);
    stage_half(Ag, ldA, baseA + 128 * rsA, rsA, 0, sm + 8192,  w, l);
    stage_half(Bg, ldB, n0,       1, 0, sm + 16384, w, l);
    stage_half(Bg, ldB, n0 + 128, 1, 0, sm + 24576, w, l);

    for (int t = 0; t < NT; ++t) {
        u16* bufA  = sm + (t & 1) * 32768;
        u16* bufB  = bufA + 16384;
        u16* nbufA = sm + ((t + 1) & 1) * 32768;
        u16* nbufB = nbufA + 16384;
        const int kt1 = (t + 1) * 64;

        // ---- phase 1: stage A(t+1); gate tile t; B frags + quad 0 ----
        if (t + 1 < NT) {
            stage_half(Ag, ldA, baseA,             rsA, kt1, nbufA,        w, l);
            stage_half(Ag, ldA, baseA + 128 * rsA, rsA, kt1, nbufA + 8192, w, l);
            asm volatile("s_waitcnt vmcnt(4)" ::: "memory");
        } else {
            asm volatile("s_waitcnt vmcnt(0)" ::: "memory");
        }
        BAR();
        bf16x8 bfr[4][2];
        #pragma unroll
        for (int nf = 0; nf < 4; ++nf) {
            int row = wn + nf * 16 + p;
            bfr[nf][0] = *(const bf16x8*)(bufB + row * 64 + ((0 + g) ^ (row & 7)) * 8);
            bfr[nf][1] = *(const bf16x8*)(bufB + row * 64 + ((4 + g) ^ (row & 7)) * 8);
        }
        QUAD(0);
        BAR();
        // ---- phase 2: stage B(t+1) h0; quad 1 ----
        if (t + 1 < NT) stage_half(Bg, ldB, n0, 1, kt1, nbufB, w, l);
        QUAD(1);
        BAR();
        // ---- phase 3: stage B(t+1) h1; quad 2 ----
        if (t + 1 < NT) stage_half(Bg, ldB, n0 + 128, 1, kt1, nbufB + 8192, w, l);
        QUAD(2);
        BAR();
        // ---- phase 4: quad 3 ----
        QUAD(3);
        BAR();
    }
}

// ===========================================================================
// Old 128x128 core (k2 split-K scores)
// ===========================================================================
__device__ __forceinline__ void stage128(
    const u16* __restrict__ Ag, int ldA, const u16* __restrict__ Bg, int ldB,
    int m0, int n0, int k0, u16* Asm, u16* Bsm, int w, int l)
{
    const int row = (w & 1) * 64 + l;
    const int kbh = w >> 1;
    #pragma unroll
    for (int r = 0; r < 4; ++r) {
        const int kb = r * 2 + kbh;
        const u16* sa = Ag + (size_t)(m0 + row) * ldA + k0 + kb * 8;
        const u16* sb = Bg + (size_t)(n0 + row) * ldB + k0 + kb * 8;
        __builtin_amdgcn_global_load_lds(
            (const __attribute__((address_space(1))) unsigned int*)sa,
            (__attribute__((address_space(3))) unsigned int*)(Asm + (size_t)(r * 256 + w * 64) * 8),
            16, 0, 0);
        __builtin_amdgcn_global_load_lds(
            (const __attribute__((address_space(1))) unsigned int*)sb,
            (__attribute__((address_space(3))) unsigned int*)(Bsm + (size_t)(r * 256 + w * 64) * 8),
            16, 0, 0);
    }
}

__device__ __forceinline__ void compute128(
    const u16* Asm, const u16* Bsm, int wm, int wn, int p, int g, f32x4 acc[4][4])
{
    #pragma unroll
    for (int ks = 0; ks < 2; ++ks) {
        const int kb = ks * 4 + g;
        bf16x8 af[4], bfr[4];
        #pragma unroll
        for (int i = 0; i < 4; ++i)
            af[i] = *(const bf16x8*)(Asm + (size_t)(kb * 128 + wm + i * 16 + p) * 8);
        #pragma unroll
        for (int j = 0; j < 4; ++j)
            bfr[j] = *(const bf16x8*)(Bsm + (size_t)(kb * 128 + wn + j * 16 + p) * 8);
        #pragma unroll
        for (int i = 0; i < 4; ++i)
            #pragma unroll
            for (int j = 0; j < 4; ++j)
                acc[i][j] = __builtin_amdgcn_mfma_f32_16x16x32_bf16(af[i], bfr[j], acc[i][j], 0, 0, 0);
    }
}

__device__ __forceinline__ void gemm128(
    const u16* __restrict__ Ag, int ldA, const u16* __restrict__ Bg, int ldB,
    int m0, int n0, int kbeg, int ntiles, u16* Asm, u16* Bsm, f32x4 acc[4][4])
{
    const int tid = threadIdx.x;
    const int l = tid & 63, w = tid >> 6;
    const int p = l & 15, g = l >> 4;
    const int wm = (w >> 1) * 64, wn = (w & 1) * 64;

    stage128(Ag, ldA, Bg, ldB, m0, n0, kbeg, Asm, Bsm, w, l);
    for (int t = 0; t < ntiles; ++t) {
        __syncthreads();
        compute128(Asm, Bsm, wm, wn, p, g, acc);
        __syncthreads();
        if (t + 1 < ntiles)
            stage128(Ag, ldA, Bg, ldB, m0, n0, kbeg + (t + 1) * 64, Asm, Bsm, w, l);
    }
}

// ---------------------------------------------------------------------------
// K0: xT[b][n][c] (bf16) = x[b][c][n] (f32)
// ---------------------------------------------------------------------------
__global__ __launch_bounds__(256) void k0_xpose(const float* __restrict__ x, u16* __restrict__ xT)
{
    __shared__ float Tx[64 * 65];
    const int tid = threadIdx.x;
    const int b = blockIdx.z, c0 = blockIdx.y * 64, n0 = blockIdx.x * 64;
    const float* xb = x + (size_t)b * 512 * 4096;
    #pragma unroll
    for (int r = 0; r < 4; ++r) {
        int crow = (tid >> 4) + r * 16;
        int ncol = (tid & 15) * 4;
        float4 v = *(const float4*)(xb + (size_t)(c0 + crow) * 4096 + n0 + ncol);
        Tx[(ncol + 0) * 65 + crow] = v.x;
        Tx[(ncol + 1) * 65 + crow] = v.y;
        Tx[(ncol + 2) * 65 + crow] = v.z;
        Tx[(ncol + 3) * 65 + crow] = v.w;
    }
    __syncthreads();
    u16* ob = xT + (size_t)b * 4096 * 512;
    #pragma unroll
    for (int cc = 0; cc < 2; ++cc) {
        int id = cc * 256 + tid;
        int nrow = id >> 3;
        int cch = (id & 7) * 8;
        u16x8 u;
        #pragma unroll
        for (int j = 0; j < 8; ++j) u[j] = f2bf(Tx[nrow * 65 + cch + j]);
        *(u16x8*)(ob + (size_t)(n0 + nrow) * 512 + c0 + cch) = u;
    }
}

// K0b: weights f32 -> bf16 (wq,wk stacked into wqk[512][512])
__global__ __launch_bounds__(256) void k0b_wconv(
    const float* __restrict__ s0, const float* __restrict__ s1,
    const float* __restrict__ s2, const float* __restrict__ s3,
    u16* __restrict__ d0, u16* __restrict__ d1, u16* __restrict__ d2, u16* __restrict__ d3)
{
    const int sel = blockIdx.y;
    const float* s = sel == 0 ? s0 : sel == 1 ? s1 : sel == 2 ? s2 : s3;
    u16* d = sel == 0 ? d0 : sel == 1 ? d1 : sel == 2 ? d2 : d3;
    int i = (blockIdx.x * 256 + threadIdx.x) * 4;
    float4 v = *(const float4*)(s + i);
    u16x4 u = {f2bf(v.x), f2bf(v.y), f2bf(v.z), f2bf(v.w)};
    *(u16x4*)(d + i) = u;
}

// ---------------------------------------------------------------------------
// K1a: q,k = wqk . xT^T + bias. M=512 (q:0-255, k:256-511), N=4096, K=512.
// grid (16, 2, 16), 512 threads.
// ---------------------------------------------------------------------------
__global__ __launch_bounds__(512, 2) void k1a_qk(
    const u16* __restrict__ wqk, const float* __restrict__ bq, const float* __restrict__ bk,
    const u16* __restrict__ xT, u16* __restrict__ q, u16* __restrict__ kmat)
{
    __shared__ u16 sm[65536];
    const int b  = blockIdx.z;
    const int m0 = blockIdx.y * 256;
    const int n0 = blockIdx.x * 256;
    const u16* B = xT + (size_t)b * 4096 * 512;

    f32x4 acc[8][4] = {};
    gemm256<8>(wqk, 512, m0, 1, B, 512, n0, sm, acc);

    const int tid = threadIdx.x;
    const int l = tid & 63, w = tid >> 6;
    const int p = l & 15, g = l >> 4;
    const int wm = (w >> 2) * 128, wn = (w & 3) * 64;

    const float* bias = (m0 == 0) ? bq : bk;
    u16* outp = ((m0 == 0) ? q : kmat) + ((size_t)b << 20);
    #pragma unroll
    for (int mf = 0; mf < 8; ++mf)
        #pragma unroll
        for (int nf = 0; nf < 4; ++nf) {
            int n = n0 + wn + nf * 16 + p;
            #pragma unroll
            for (int r = 0; r < 4; ++r) {
                int mloc = wm + mf * 16 + g * 4 + r;
                outp[(size_t)mloc * 4096 + n] = f2bf(acc[mf][nf][r] + bias[mloc]);
            }
        }
}

// ---------------------------------------------------------------------------
// K1b: vT[n][d] = xT[n][:] . Wv[d][:] + bv[d]. M=4096, N=256, K=512.
// grid (16, 1, 16), 512 threads.
// ---------------------------------------------------------------------------
__global__ __launch_bounds__(512, 2) void k1b_v(
    const u16* __restrict__ xT, const u16* __restrict__ wv, const float* __restrict__ bv,
    u16* __restrict__ vT)
{
    __shared__ u16 sm[65536];
    const int b  = blockIdx.z;
    const int m0 = blockIdx.x * 256;
    const u16* A = xT + (size_t)b * 4096 * 512;

    f32x4 acc[8][4] = {};
    gemm256<8>(A, 512, m0, 1, wv, 512, 0, sm, acc);

    const int tid = threadIdx.x;
    const int l = tid & 63, w = tid >> 6;
    const int p = l & 15, g = l >> 4;
    const int wm = (w >> 2) * 128, wn = (w & 3) * 64;

    u16* outp = vT + ((size_t)b << 20);
    #pragma unroll
    for (int nf = 0; nf < 4; ++nf) {
        int d = wn + nf * 16 + p;
        float bvv = bv[d];
        #pragma unroll
        for (int mf = 0; mf < 8; ++mf) {
            #pragma unroll
            for (int r = 0; r < 4; ++r) {
                int row = m0 + wm + mf * 16 + g * 4 + r;
                outp[(size_t)row * 256 + d] = f2bf(acc[mf][nf][r] + bvv);
            }
        }
    }
}

// ---------------------------------------------------------------------------
// K2: score partials, split-K=8 (128^2 core). grid (2, 2, 128)
// ---------------------------------------------------------------------------
__global__ __launch_bounds__(256) void k2_scores(
    const u16* __restrict__ q, const u16* __restrict__ kmat, float* __restrict__ spart)
{
    __shared__ u16 sm[16384];
    const int bz = blockIdx.z;
    const int b = bz >> 3, split = bz & 7;
    const int m0 = blockIdx.y * 128, n0 = blockIdx.x * 128;
    const u16* A = q    + ((size_t)b << 20);
    const u16* B = kmat + ((size_t)b << 20);

    f32x4 acc[4][4] = {};
    gemm128(A, 4096, B, 4096, m0, n0, split * 512, 8, sm, sm + 8192, acc);

    const int tid = threadIdx.x;
    const int l = tid & 63, w = tid >> 6;
    const int p = l & 15, g = l >> 4;
    const int wm = (w >> 1) * 64, wn = (w & 1) * 64;
    float* sp = spart + ((size_t)split * 16 + b) * 65536;
    #pragma unroll
    for (int mf = 0; mf < 4; ++mf)
        #pragma unroll
        for (int nf = 0; nf < 4; ++nf) {
            int n = n0 + wn + nf * 16 + p;
            #pragma unroll
            for (int r = 0; r < 4; ++r) {
                int m = m0 + wm + mf * 16 + g * 4 + r;
                sp[(size_t)m * 256 + n] = acc[mf][nf][r] * 0.015625f;
            }
        }
}

// ---------------------------------------------------------------------------
// K3: reduce 8 split partials + softmax over d -> bf16 attn
// ---------------------------------------------------------------------------
__global__ __launch_bounds__(256) void k3_softmax(
    const float* __restrict__ sp, u16* __restrict__ attn)
{
    const int row = blockIdx.x;
    const int tid = threadIdx.x;
    const size_t STRIDE = (size_t)16 * 65536;
    const size_t base = (size_t)row * 256 + tid;

    float s = 0.f;
    #pragma unroll
    for (int i = 0; i < 8; ++i) s += sp[base + i * STRIDE];

    __shared__ float red[4];
    float m = s;
    #pragma unroll
    for (int off = 32; off >= 1; off >>= 1) m = fmaxf(m, __shfl_xor(m, off));
    if ((tid & 63) == 0) red[tid >> 6] = m;
    __syncthreads();
    m = fmaxf(fmaxf(red[0], red[1]), fmaxf(red[2], red[3]));

    float e = expf(s - m);
    float t = e;
    #pragma unroll
    for (int off = 32; off >= 1; off >>= 1) t += __shfl_xor(t, off);
    __syncthreads();
    if ((tid & 63) == 0) red[tid >> 6] = t;
    __syncthreads();
    t = red[0] + red[1] + red[2] + red[3];

    attn[base] = f2bf(e / t);
}

// ---------------------------------------------------------------------------
// K4: outT3[b][sh][co][nh] = sum_d attn[b][co][d] * vT[b][16nh+sh][d]
// Per (b,sh): M=256 (nh, via row-stride-16 A load: row m -> vT row 16m+sh),
// N=256 (co), K=256 (d). grid (16=sh, 1, 16=b), 512 threads.
// Thread's r=0..3 are consecutive nh -> direct u16x4 stores, no LDS epilogue.
// ---------------------------------------------------------------------------
__global__ __launch_bounds__(512, 2) void k4_pv(
    const u16* __restrict__ attn, const u16* __restrict__ vT, u16* __restrict__ outT3)
{
    __shared__ u16 sm[65536];
    const int b  = blockIdx.z;
    const int sh = blockIdx.x;
    const u16* A = vT   + ((size_t)b << 20);   // rows 16m+sh
    const u16* B = attn + ((size_t)b << 16);

    f32x4 acc[8][4] = {};
    gemm256<4>(A, 256, sh, 16, B, 256, 0, sm, acc);

    const int tid = threadIdx.x;
    const int l = tid & 63, w = tid >> 6;
    const int p = l & 15, g = l >> 4;
    const int wm = (w >> 2) * 128, wn = (w & 3) * 64;

    u16* outp = outT3 + (((size_t)b * 16 + sh) << 16);
    #pragma unroll
    for (int mf = 0; mf < 8; ++mf)
        #pragma unroll
        for (int nf = 0; nf < 4; ++nf) {
            int co  = wn + nf * 16 + p;
            int nh0 = wm + mf * 16 + g * 4;
            u16x4 u = {f2bf(acc[mf][nf][0]), f2bf(acc[mf][nf][1]),
                       f2bf(acc[mf][nf][2]), f2bf(acc[mf][nf][3])};
            *(u16x4*)(outp + (size_t)co * 256 + nh0) = u;
        }
}

// ---------------------------------------------------------------------------
// K5: final[b][c][sh*256+slo] = sum_nh Wo[c][nh] * outT3[b][sh][slo][nh] + bo[c]
// Per (b,sh): M=512 (c), N=256 (slo), K=256 (nh). grid (1, 2, 256), 512 thr.
// ---------------------------------------------------------------------------
__global__ __launch_bounds__(512, 2) void k5_final(
    const u16* __restrict__ wo, const float* __restrict__ bo,
    const u16* __restrict__ outT3, float* __restrict__ out)
{
    __shared__ u16 sm[65536];
    const int bz = blockIdx.z;               // b*16 + sh
    const int b  = bz >> 4, sh = bz & 15;
    const int m0 = blockIdx.y * 256;
    const u16* B = outT3 + ((size_t)bz << 16);

    f32x4 acc[8][4] = {};
    gemm256<4>(wo, 256, m0, 1, B, 256, 0, sm, acc);

    const int tid = threadIdx.x;
    const int l = tid & 63, w = tid >> 6;
    const int p = l & 15, g = l >> 4;
    const int wm = (w >> 2) * 128, wn = (w & 3) * 64;

    float* ob = out + (size_t)b * 2097152 + (size_t)sh * 256;
    #pragma unroll
    for (int mf = 0; mf < 8; ++mf)
        #pragma unroll
        for (int nf = 0; nf < 4; ++nf) {
            int slo = wn + nf * 16 + p;
            #pragma unroll
            for (int r = 0; r < 4; ++r) {
                int m = m0 + wm + mf * 16 + g * 4 + r;
                ob[(size_t)m * 4096 + slo] = acc[mf][nf][r] + bo[m];
            }
        }
}

// ---------------------------------------------------------------------------
extern "C" void kernel_launch(void* const* d_in, const int* in_sizes, int n_in,
                              void* d_out, int out_size, void* d_ws, size_t ws_size,
                              hipStream_t stream) {
    (void)in_sizes; (void)n_in; (void)out_size; (void)ws_size;
    const float* x  = (const float*)d_in[0];
    const float* Wq = (const float*)d_in[1];
    const float* bq = (const float*)d_in[2];
    const float* Wk = (const float*)d_in[3];
    const float* bk = (const float*)d_in[4];
    const float* Wv = (const float*)d_in[5];
    const float* bv = (const float*)d_in[6];
    const float* Wo = (const float*)d_in[7];
    const float* bo = (const float*)d_in[8];
    float* out = (float*)d_out;

    char* ws = (char*)d_ws;
    u16* xT   = (u16*)(ws + 0);             // 64MB, dead after k1b
    u16* q    = (u16*)(ws + 67108864);      // 32MB, dead after k2
    u16* kmat = (u16*)(ws + 100663296);     // 32MB, dead after k2
    u16* vT   = (u16*)(ws + 134217728);     // 32MB, dead after k4
    float* spart = (float*)(ws + 0);        // 32MB, aliases xT
    u16* attn    = (u16*)(ws + 67108864);   // 2MB, aliases q
    u16* outT3   = (u16*)(ws + 100663296);  // 32MB, aliases kmat
    u16* wqk  = (u16*)(ws + 167772160);     // 512KB [512][512] (q rows then k rows)
    u16* wv   = (u16*)(ws + 168296448);     // 256KB [256][512]
    u16* wo   = (u16*)(ws + 168558592);     // 256KB [512][256]

    k0b_wconv <<<dim3(128, 4),    dim3(256), 0, stream>>>(Wq, Wk, Wv, Wo,
                                                          wqk, wqk + 131072, wv, wo);
    k0_xpose  <<<dim3(64, 8, 16), dim3(256), 0, stream>>>(x, xT);
    k1a_qk    <<<dim3(16, 2, 16), dim3(512), 0, stream>>>(wqk, bq, bk, xT, q, kmat);
    k1b_v     <<<dim3(16, 1, 16), dim3(512), 0, stream>>>(xT, wv, bv, vT);
    k2_scores <<<dim3(2, 2, 128), dim3(256), 0, stream>>>(q, kmat, spart);
    k3_softmax<<<dim3(4096),      dim3(256), 0, stream>>>(spart, attn);
    k4_pv     <<<dim3(16, 1, 16), dim3(512), 0, stream>>>(attn, vT, outT3);
    k5_final  <<<dim3(1, 2, 256), dim3(512), 0, stream>>>(wo, bo, outT3, out);
}

// Round 5
// 200.376 us; speedup vs baseline: 5.5281x; 1.0986x over previous
//
#include <hip/hip_runtime.h>
#include <math.h>

typedef unsigned short u16;
typedef __bf16 bf16x8 __attribute__((ext_vector_type(8)));
typedef float f32x4 __attribute__((ext_vector_type(4)));
typedef unsigned short u16x4 __attribute__((ext_vector_type(4)));
typedef unsigned short u16x8 __attribute__((ext_vector_type(8)));

__device__ __forceinline__ u16 f2bf(float f) {
    unsigned int u = __float_as_uint(f);
    return (u16)((u + 0x7FFF + ((u >> 16) & 1)) >> 16);
}

#define BAR() do { __builtin_amdgcn_sched_barrier(0); __builtin_amdgcn_s_barrier(); __builtin_amdgcn_sched_barrier(0); } while (0)

// ===========================================================================
// 256x256 8-wave deep-pipelined bf16 GEMM (T2+T3+T4+T5), 512 threads.
// A: logical row m -> global row baseA + m*rsA, k-contig (ldA).
// B: logical row n -> global row n0 + n, k-contig (ldB).
// LDS 128KB = 2 bufs x (A 32KB + B 32KB), K-tile 64.
// 16B-chunk swizzle kc^(row&7): pre-swizzled GLOBAL source + linear LDS dest
// (global_load_lds), read back with the same XOR (involution).
// Pipeline: stage tile t+1 during tile t (A @phase1, B @phases2,3);
// single s_waitcnt vmcnt(4) per K-tile (never 0 in main loop).
// Ledger: 8 outstanding at each phase-1 entry; +4 (A(t+1)) then vmcnt(4)
// retains exactly those 4 -> tile t fully landed.
// ===========================================================================
__device__ __forceinline__ void stage_half(
    const u16* __restrict__ g, int ld, int row0, int rstride, int kt,
    u16* lds, int w, int l)
{
    #pragma unroll
    for (int qq = 0; qq < 2; ++qq) {
        const int c0 = qq * 512 + w * 64;    // wave-uniform chunk base
        const int c  = c0 + l;
        const int r  = c >> 3, kc = c & 7;
        const int kcg = kc ^ (r & 7);
        const u16* src = g + (size_t)(row0 + r * rstride) * ld + kt + kcg * 8;
        __builtin_amdgcn_global_load_lds(
            (const __attribute__((address_space(1))) unsigned int*)src,
            (__attribute__((address_space(3))) unsigned int*)(lds + (size_t)c0 * 8),
            16, 0, 0);
    }
}

#define QUAD(q_) do {                                                          \
    bf16x8 af0[2], af1[2];                                                     \
    { int row = wm + ((q_) * 2 + 0) * 16 + p;                                  \
      af0[0] = *(const bf16x8*)(bufA + row * 64 + ((0 + g) ^ (row & 7)) * 8);  \
      af0[1] = *(const bf16x8*)(bufA + row * 64 + ((4 + g) ^ (row & 7)) * 8); }\
    { int row = wm + ((q_) * 2 + 1) * 16 + p;                                  \
      af1[0] = *(const bf16x8*)(bufA + row * 64 + ((0 + g) ^ (row & 7)) * 8);  \
      af1[1] = *(const bf16x8*)(bufA + row * 64 + ((4 + g) ^ (row & 7)) * 8); }\
    __builtin_amdgcn_s_setprio(1);                                             \
    _Pragma("unroll")                                                          \
    for (int nf = 0; nf < 4; ++nf) {                                           \
        acc[(q_)*2+0][nf] = __builtin_amdgcn_mfma_f32_16x16x32_bf16(af0[0], bfr[nf][0], acc[(q_)*2+0][nf], 0, 0, 0); \
        acc[(q_)*2+0][nf] = __builtin_amdgcn_mfma_f32_16x16x32_bf16(af0[1], bfr[nf][1], acc[(q_)*2+0][nf], 0, 0, 0); \
        acc[(q_)*2+1][nf] = __builtin_amdgcn_mfma_f32_16x16x32_bf16(af1[0], bfr[nf][0], acc[(q_)*2+1][nf], 0, 0, 0); \
        acc[(q_)*2+1][nf] = __builtin_amdgcn_mfma_f32_16x16x32_bf16(af1[1], bfr[nf][1], acc[(q_)*2+1][nf], 0, 0, 0); \
    }                                                                          \
    __builtin_amdgcn_s_setprio(0);                                             \
} while (0)

template<int NT>
__device__ __forceinline__ void gemm256(
    const u16* __restrict__ Ag, int ldA, int baseA, int rsA,
    const u16* __restrict__ Bg, int ldB, int n0,
    u16* sm, f32x4 (&acc)[8][4])
{
    const int tid = threadIdx.x;
    const int l = tid & 63, w = tid >> 6;
    const int p = l & 15, g = l >> 4;
    const int wm = (w >> 2) * 128;   // 2 M-waves
    const int wn = (w & 3) * 64;     // 4 N-waves

    // prologue: stage tile 0 (8 loads outstanding)
    stage_half(Ag, ldA, baseA,             rsA, 0, sm,         w, l);
    stage_half(Ag, ldA, baseA + 128 * rsA, rsA, 0, sm + 8192,  w, l);
    stage_half(Bg, ldB, n0,       1, 0, sm + 16384, w, l);
    stage_half(Bg, ldB, n0 + 128, 1, 0, sm + 24576, w, l);

    for (int t = 0; t < NT; ++t) {
        u16* bufA  = sm + (t & 1) * 32768;
        u16* bufB  = bufA + 16384;
        u16* nbufA = sm + ((t + 1) & 1) * 32768;
        u16* nbufB = nbufA + 16384;
        const int kt1 = (t + 1) * 64;

        // ---- phase 1: stage A(t+1); gate tile t; B frags + quad 0 ----
        if (t + 1 < NT) {
            stage_half(Ag, ldA, baseA,             rsA, kt1, nbufA,        w, l);
            stage_half(Ag, ldA, baseA + 128 * rsA, rsA, kt1, nbufA + 8192, w, l);
            asm volatile("s_waitcnt vmcnt(4)" ::: "memory");
        } else {
            asm volatile("s_waitcnt vmcnt(0)" ::: "memory");
        }
        BAR();
        bf16x8 bfr[4][2];
        #pragma unroll
        for (int nf = 0; nf < 4; ++nf) {
            int row = wn + nf * 16 + p;
            bfr[nf][0] = *(const bf16x8*)(bufB + row * 64 + ((0 + g) ^ (row & 7)) * 8);
            bfr[nf][1] = *(const bf16x8*)(bufB + row * 64 + ((4 + g) ^ (row & 7)) * 8);
        }
        QUAD(0);
        BAR();
        // ---- phase 2: stage B(t+1) h0; quad 1 ----
        if (t + 1 < NT) stage_half(Bg, ldB, n0, 1, kt1, nbufB, w, l);
        QUAD(1);
        BAR();
        // ---- phase 3: stage B(t+1) h1; quad 2 ----
        if (t + 1 < NT) stage_half(Bg, ldB, n0 + 128, 1, kt1, nbufB + 8192, w, l);
        QUAD(2);
        BAR();
        // ---- phase 4: quad 3 ----
        QUAD(3);
        BAR();
    }
}

// ---------------------------------------------------------------------------
// K0: merged prep. z<16: xT[b][n][c] (bf16) = x[b][c][n] (f32).
// z==16: weight f32->bf16 conversion (512 blocks exactly).
// ---------------------------------------------------------------------------
__global__ __launch_bounds__(256) void k0_prep(
    const float* __restrict__ x, u16* __restrict__ xT,
    const float* __restrict__ Wq, const float* __restrict__ Wk,
    const float* __restrict__ Wv, const float* __restrict__ Wo,
    u16* __restrict__ wqk, u16* __restrict__ wv, u16* __restrict__ wo)
{
    const int tid = threadIdx.x;
    if (blockIdx.z == 16) {
        const int bid = blockIdx.y * 64 + blockIdx.x;   // 0..511
        const int sel = bid >> 7;                        // 128 blocks per matrix
        const int sub = bid & 127;
        const float* s = sel == 0 ? Wq : sel == 1 ? Wk : sel == 2 ? Wv : Wo;
        u16* d = sel == 0 ? wqk : sel == 1 ? (wqk + 131072) : sel == 2 ? wv : wo;
        int i = (sub * 256 + tid) * 4;
        float4 v = *(const float4*)(s + i);
        u16x4 u = {f2bf(v.x), f2bf(v.y), f2bf(v.z), f2bf(v.w)};
        *(u16x4*)(d + i) = u;
        return;
    }
    __shared__ float Tx[64 * 65];
    const int b = blockIdx.z, c0 = blockIdx.y * 64, n0 = blockIdx.x * 64;
    const float* xb = x + (size_t)b * 512 * 4096;
    #pragma unroll
    for (int r = 0; r < 4; ++r) {
        int crow = (tid >> 4) + r * 16;
        int ncol = (tid & 15) * 4;
        float4 v = *(const float4*)(xb + (size_t)(c0 + crow) * 4096 + n0 + ncol);
        Tx[(ncol + 0) * 65 + crow] = v.x;
        Tx[(ncol + 1) * 65 + crow] = v.y;
        Tx[(ncol + 2) * 65 + crow] = v.z;
        Tx[(ncol + 3) * 65 + crow] = v.w;
    }
    __syncthreads();
    u16* ob = xT + (size_t)b * 4096 * 512;
    #pragma unroll
    for (int cc = 0; cc < 2; ++cc) {
        int id = cc * 256 + tid;
        int nrow = id >> 3;
        int cch = (id & 7) * 8;
        u16x8 u;
        #pragma unroll
        for (int j = 0; j < 8; ++j) u[j] = f2bf(Tx[nrow * 65 + cch + j]);
        *(u16x8*)(ob + (size_t)(n0 + nrow) * 512 + c0 + cch) = u;
    }
}

// ---------------------------------------------------------------------------
// K1: merged q/k/v. grid (16, 3, 16), 512 threads.
// y<2:  q,k = wqk . xT^T + bias  (m0 = y*256, n0 = x*256)
// y==2: vT[n][d] = xT[n][:] . Wv[d][:] + bv[d]  (m0 = x*256 over spatial)
// ---------------------------------------------------------------------------
__global__ __launch_bounds__(512, 2) void k1_qkv(
    const u16* __restrict__ wqk, const u16* __restrict__ wv,
    const float* __restrict__ bq, const float* __restrict__ bk, const float* __restrict__ bv,
    const u16* __restrict__ xT, u16* __restrict__ q, u16* __restrict__ kmat,
    u16* __restrict__ vT)
{
    __shared__ u16 sm[65536];
    const int b = blockIdx.z;
    const int y = blockIdx.y;
    const u16* xb = xT + (size_t)b * 4096 * 512;

    const int tid = threadIdx.x;
    const int l = tid & 63, w = tid >> 6;
    const int p = l & 15, g = l >> 4;
    const int wm = (w >> 2) * 128, wn = (w & 3) * 64;

    f32x4 acc[8][4] = {};

    if (y < 2) {
        const int m0 = y * 256;
        const int n0 = blockIdx.x * 256;
        gemm256<8>(wqk, 512, m0, 1, xb, 512, n0, sm, acc);

        const float* bias = (y == 0) ? bq : bk;
        u16* outp = ((y == 0) ? q : kmat) + ((size_t)b << 20);
        #pragma unroll
        for (int mf = 0; mf < 8; ++mf)
            #pragma unroll
            for (int nf = 0; nf < 4; ++nf) {
                int n = n0 + wn + nf * 16 + p;
                #pragma unroll
                for (int r = 0; r < 4; ++r) {
                    int mloc = wm + mf * 16 + g * 4 + r;
                    outp[(size_t)mloc * 4096 + n] = f2bf(acc[mf][nf][r] + bias[mloc]);
                }
            }
    } else {
        const int m0 = blockIdx.x * 256;
        gemm256<8>(xb, 512, m0, 1, wv, 512, 0, sm, acc);

        u16* outp = vT + ((size_t)b << 20);
        #pragma unroll
        for (int nf = 0; nf < 4; ++nf) {
            int d = wn + nf * 16 + p;
            float bvv = bv[d];
            #pragma unroll
            for (int mf = 0; mf < 8; ++mf) {
                #pragma unroll
                for (int r = 0; r < 4; ++r) {
                    int row = m0 + wm + mf * 16 + g * 4 + r;
                    outp[(size_t)row * 256 + d] = f2bf(acc[mf][nf][r] + bvv);
                }
            }
        }
    }
}

// ---------------------------------------------------------------------------
// K2: score partials, split-K=16, pipelined 256^2 core.
// grid (16=split, 1, 16=b), 512 threads. K-slice = split*256 (pointer offset).
// ---------------------------------------------------------------------------
__global__ __launch_bounds__(512, 2) void k2_scores(
    const u16* __restrict__ q, const u16* __restrict__ kmat, float* __restrict__ spart)
{
    __shared__ u16 sm[65536];
    const int b = blockIdx.z;
    const int split = blockIdx.x;
    const u16* A = q    + ((size_t)b << 20) + split * 256;
    const u16* B = kmat + ((size_t)b << 20) + split * 256;

    f32x4 acc[8][4] = {};
    gemm256<4>(A, 4096, 0, 1, B, 4096, 0, sm, acc);

    const int tid = threadIdx.x;
    const int l = tid & 63, w = tid >> 6;
    const int p = l & 15, g = l >> 4;
    const int wm = (w >> 2) * 128, wn = (w & 3) * 64;

    float* sp = spart + ((size_t)split * 16 + b) * 65536;
    #pragma unroll
    for (int mf = 0; mf < 8; ++mf)
        #pragma unroll
        for (int nf = 0; nf < 4; ++nf) {
            int n = wn + nf * 16 + p;
            #pragma unroll
            for (int r = 0; r < 4; ++r) {
                int m = wm + mf * 16 + g * 4 + r;
                sp[(size_t)m * 256 + n] = acc[mf][nf][r] * 0.015625f;
            }
        }
}

// ---------------------------------------------------------------------------
// K3: reduce 16 split partials + softmax over d -> bf16 attn
// ---------------------------------------------------------------------------
__global__ __launch_bounds__(256) void k3_softmax(
    const float* __restrict__ sp, u16* __restrict__ attn)
{
    const int row = blockIdx.x;
    const int tid = threadIdx.x;
    const size_t STRIDE = (size_t)16 * 65536;
    const size_t base = (size_t)row * 256 + tid;

    float s = 0.f;
    #pragma unroll
    for (int i = 0; i < 16; ++i) s += sp[base + i * STRIDE];

    __shared__ float red[4];
    float m = s;
    #pragma unroll
    for (int off = 32; off >= 1; off >>= 1) m = fmaxf(m, __shfl_xor(m, off));
    if ((tid & 63) == 0) red[tid >> 6] = m;
    __syncthreads();
    m = fmaxf(fmaxf(red[0], red[1]), fmaxf(red[2], red[3]));

    float e = expf(s - m);
    float t = e;
    #pragma unroll
    for (int off = 32; off >= 1; off >>= 1) t += __shfl_xor(t, off);
    __syncthreads();
    if ((tid & 63) == 0) red[tid >> 6] = t;
    __syncthreads();
    t = red[0] + red[1] + red[2] + red[3];

    attn[base] = f2bf(e / t);
}

// ---------------------------------------------------------------------------
// K4: outT3[b][sh][co][nh] = sum_d attn[b][co][d] * vT[b][16nh+sh][d]
// Per (b,sh): M=256 (nh via rstride-16 A rows), N=256 (co), K=256 (d).
// grid (16=sh, 1, 16=b), 512 threads.
// ---------------------------------------------------------------------------
__global__ __launch_bounds__(512, 2) void k4_pv(
    const u16* __restrict__ attn, const u16* __restrict__ vT, u16* __restrict__ outT3)
{
    __shared__ u16 sm[65536];
    const int b  = blockIdx.z;
    const int sh = blockIdx.x;
    const u16* A = vT   + ((size_t)b << 20);   // rows 16m+sh
    const u16* B = attn + ((size_t)b << 16);

    f32x4 acc[8][4] = {};
    gemm256<4>(A, 256, sh, 16, B, 256, 0, sm, acc);

    const int tid = threadIdx.x;
    const int l = tid & 63, w = tid >> 6;
    const int p = l & 15, g = l >> 4;
    const int wm = (w >> 2) * 128, wn = (w & 3) * 64;

    u16* outp = outT3 + (((size_t)b * 16 + sh) << 16);
    #pragma unroll
    for (int mf = 0; mf < 8; ++mf)
        #pragma unroll
        for (int nf = 0; nf < 4; ++nf) {
            int co  = wn + nf * 16 + p;
            int nh0 = wm + mf * 16 + g * 4;
            u16x4 u = {f2bf(acc[mf][nf][0]), f2bf(acc[mf][nf][1]),
                       f2bf(acc[mf][nf][2]), f2bf(acc[mf][nf][3])};
            *(u16x4*)(outp + (size_t)co * 256 + nh0) = u;
        }
}

// ---------------------------------------------------------------------------
// K5: final[b][c][sh*256+slo] = sum_nh Wo[c][nh] * outT3[b][sh][slo][nh] + bo[c]
// Per (b,sh): M=512 (c), N=256 (slo), K=256 (nh). grid (1, 2, 256), 512 thr.
// ---------------------------------------------------------------------------
__global__ __launch_bounds__(512, 2) void k5_final(
    const u16* __restrict__ wo, const float* __restrict__ bo,
    const u16* __restrict__ outT3, float* __restrict__ out)
{
    __shared__ u16 sm[65536];
    const int bz = blockIdx.z;               // b*16 + sh
    const int b  = bz >> 4, sh = bz & 15;
    const int m0 = blockIdx.y * 256;
    const u16* B = outT3 + ((size_t)bz << 16);

    f32x4 acc[8][4] = {};
    gemm256<4>(wo, 256, m0, 1, B, 256, 0, sm, acc);

    const int tid = threadIdx.x;
    const int l = tid & 63, w = tid >> 6;
    const int p = l & 15, g = l >> 4;
    const int wm = (w >> 2) * 128, wn = (w & 3) * 64;

    float* ob = out + (size_t)b * 2097152 + (size_t)sh * 256;
    #pragma unroll
    for (int mf = 0; mf < 8; ++mf)
        #pragma unroll
        for (int nf = 0; nf < 4; ++nf) {
            int slo = wn + nf * 16 + p;
            #pragma unroll
            for (int r = 0; r < 4; ++r) {
                int m = m0 + wm + mf * 16 + g * 4 + r;
                ob[(size_t)m * 4096 + slo] = acc[mf][nf][r] + bo[m];
            }
        }
}

// ---------------------------------------------------------------------------
extern "C" void kernel_launch(void* const* d_in, const int* in_sizes, int n_in,
                              void* d_out, int out_size, void* d_ws, size_t ws_size,
                              hipStream_t stream) {
    (void)in_sizes; (void)n_in; (void)out_size; (void)ws_size;
    const float* x  = (const float*)d_in[0];
    const float* Wq = (const float*)d_in[1];
    const float* bq = (const float*)d_in[2];
    const float* Wk = (const float*)d_in[3];
    const float* bk = (const float*)d_in[4];
    const float* Wv = (const float*)d_in[5];
    const float* bv = (const float*)d_in[6];
    const float* Wo = (const float*)d_in[7];
    const float* bo = (const float*)d_in[8];
    float* out = (float*)d_out;

    char* ws = (char*)d_ws;
    u16* xT   = (u16*)(ws + 0);             // 67.1MB, dead after k1
    u16* q    = (u16*)(ws + 67108864);      // 33.5MB, dead after k2
    u16* kmat = (u16*)(ws + 100663296);     // 33.5MB, dead after k2
    u16* vT   = (u16*)(ws + 134217728);     // 33.5MB, dead after k4
    float* spart = (float*)(ws + 0);        // 67.1MB f32 (16 splits), aliases xT
    u16* attn    = (u16*)(ws + 67108864);   // 2MB, aliases q
    u16* outT3   = (u16*)(ws + 100663296);  // 33.5MB, aliases kmat
    u16* wqk  = (u16*)(ws + 167772160);     // 512KB [512][512] (q rows then k rows)
    u16* wv   = (u16*)(ws + 168296448);     // 256KB [256][512]
    u16* wo   = (u16*)(ws + 168558592);     // 256KB [512][256]

    k0_prep   <<<dim3(64, 8, 17), dim3(256), 0, stream>>>(x, xT, Wq, Wk, Wv, Wo, wqk, wv, wo);
    k1_qkv    <<<dim3(16, 3, 16), dim3(512), 0, stream>>>(wqk, wv, bq, bk, bv, xT, q, kmat, vT);
    k2_scores <<<dim3(16, 1, 16), dim3(512), 0, stream>>>(q, kmat, spart);
    k3_softmax<<<dim3(4096),      dim3(256), 0, stream>>>(spart, attn);
    k4_pv     <<<dim3(16, 1, 16), dim3(512), 0, stream>>>(attn, vT, outT3);
    k5_final  <<<dim3(1, 2, 256), dim3(512), 0, stream>>>(wo, bo, outT3, out);
}

// Round 6
// 198.771 us; speedup vs baseline: 5.5728x; 1.0081x over previous
//
#include <hip/hip_runtime.h>
#include <math.h>

typedef unsigned short u16;
typedef __bf16 bf16x8 __attribute__((ext_vector_type(8)));
typedef float f32x4 __attribute__((ext_vector_type(4)));
typedef unsigned short u16x4 __attribute__((ext_vector_type(4)));
typedef unsigned short u16x8 __attribute__((ext_vector_type(8)));

__device__ __forceinline__ u16 f2bf(float f) {
    unsigned int u = __float_as_uint(f);
    return (u16)((u + 0x7FFF + ((u >> 16) & 1)) >> 16);
}

#define BAR() do { __builtin_amdgcn_sched_barrier(0); __builtin_amdgcn_s_barrier(); __builtin_amdgcn_sched_barrier(0); } while (0)

// ===========================================================================
// 256x256 8-wave GEMM core, BK=32, 4-deep LDS pipeline (prefetch 3 K-tiles).
// A: logical row m -> global row baseA + m*rsA, k-contig (ldA).
// B: logical row n -> global row n0 + n, k-contig (ldB).
// LDS = 4 bufs x (A 16KB + B 16KB) = 128KB. 2 phases per K-tile, 16 MFMA each.
// Layout: [row][kc] chunks of 8 bf16, row stride 64B -> linear, conflict-OK
// (lane(p,g) reads 16B window at row*64+g*16; (p&1,g) -> 8 disjoint 4-bank
//  windows, aggregate 128B/cyc = LDS peak; no swizzle needed at BK=32).
// Counted waits: entering tile t, instrs issued after B(t) are
// A/B(t+1), A/B(t+2), A(t+3) = 10 (steady); tail r=NT-1-t: 2->8, 1->4, 0->0.
// Buffer reuse safety: stg of tile t+3 writes buf (t-1)&3, issued after the
// end-of-tile-(t-1) barrier -> all reads of that buf are complete.
// ===========================================================================
__device__ __forceinline__ void stg(
    const u16* __restrict__ g, int ld, int row0, int rstride, int kt,
    u16* lds, int w, int l)
{
    #pragma unroll
    for (int qq = 0; qq < 2; ++qq) {
        const int c0 = qq * 512 + w * 64;        // wave-uniform chunk base
        const int c  = c0 + l;                   // chunk 0..1023: row=c>>2, kc=c&3
        const u16* src = g + (size_t)(row0 + (c >> 2) * rstride) * ld + kt + (c & 3) * 8;
        __builtin_amdgcn_global_load_lds(
            (const __attribute__((address_space(1))) unsigned int*)src,
            (__attribute__((address_space(3))) unsigned int*)(lds + (size_t)c0 * 8),
            16, 0, 0);
    }
}

template<int NT>
__device__ __forceinline__ void gemm256(
    const u16* __restrict__ Ag, int ldA, int baseA, int rsA,
    const u16* __restrict__ Bg, int ldB, int n0,
    u16* sm, f32x4 (&acc)[8][4])
{
    const int tid = threadIdx.x;
    const int l = tid & 63, w = tid >> 6;
    const int p = l & 15, g = l >> 4;
    const int wm = (w >> 2) * 128;   // 2 M-waves
    const int wn = (w & 3) * 64;     // 4 N-waves

    // prologue: stage tiles 0..2 (12 load-instrs/wave outstanding)
    #pragma unroll
    for (int t = 0; t < 3; ++t) {
        u16* buf = sm + (t & 3) * 16384;
        stg(Ag, ldA, baseA, rsA, t * 32, buf, w, l);
        stg(Bg, ldB, n0, 1, t * 32, buf + 8192, w, l);
    }

    #pragma unroll
    for (int t = 0; t < NT; ++t) {
        u16* bufA = sm + (t & 3) * 16384;
        u16* bufB = bufA + 8192;
        u16* nbuf = sm + ((t + 3) & 3) * 16384;

        // ---- phase 1: stage A(t+3); counted gate for tile t; half 1 ----
        if (t + 3 < NT) stg(Ag, ldA, baseA, rsA, (t + 3) * 32, nbuf, w, l);
        {
            const int r = NT - 1 - t;
            if (r >= 3)      asm volatile("s_waitcnt vmcnt(10)" ::: "memory");
            else if (r == 2) asm volatile("s_waitcnt vmcnt(8)"  ::: "memory");
            else if (r == 1) asm volatile("s_waitcnt vmcnt(4)"  ::: "memory");
            else             asm volatile("s_waitcnt vmcnt(0)"  ::: "memory");
        }
        BAR();
        bf16x8 bfr[4];
        #pragma unroll
        for (int nf = 0; nf < 4; ++nf) {
            int row = wn + nf * 16 + p;
            bfr[nf] = *(const bf16x8*)(bufB + row * 32 + g * 8);
        }
        {
            bf16x8 af[4];
            #pragma unroll
            for (int i = 0; i < 4; ++i) {
                int row = wm + i * 16 + p;
                af[i] = *(const bf16x8*)(bufA + row * 32 + g * 8);
            }
            __builtin_amdgcn_s_setprio(1);
            #pragma unroll
            for (int i = 0; i < 4; ++i)
                #pragma unroll
                for (int nf = 0; nf < 4; ++nf)
                    acc[i][nf] = __builtin_amdgcn_mfma_f32_16x16x32_bf16(af[i], bfr[nf], acc[i][nf], 0, 0, 0);
            __builtin_amdgcn_s_setprio(0);
        }
        // ---- phase 2: stage B(t+3); half 2 ----
        if (t + 3 < NT) stg(Bg, ldB, n0, 1, (t + 3) * 32, nbuf + 8192, w, l);
        {
            bf16x8 af[4];
            #pragma unroll
            for (int i = 0; i < 4; ++i) {
                int row = wm + (4 + i) * 16 + p;
                af[i] = *(const bf16x8*)(bufA + row * 32 + g * 8);
            }
            __builtin_amdgcn_s_setprio(1);
            #pragma unroll
            for (int i = 0; i < 4; ++i)
                #pragma unroll
                for (int nf = 0; nf < 4; ++nf)
                    acc[4 + i][nf] = __builtin_amdgcn_mfma_f32_16x16x32_bf16(af[i], bfr[nf], acc[4 + i][nf], 0, 0, 0);
            __builtin_amdgcn_s_setprio(0);
        }
        BAR();
    }
}

// ---------------------------------------------------------------------------
// K0: merged prep. z<16: xT[b][n][c] (bf16) = x[b][c][n] (f32).
// z==16: weight f32->bf16 conversion (512 blocks exactly).
// ---------------------------------------------------------------------------
__global__ __launch_bounds__(256) void k0_prep(
    const float* __restrict__ x, u16* __restrict__ xT,
    const float* __restrict__ Wq, const float* __restrict__ Wk,
    const float* __restrict__ Wv, const float* __restrict__ Wo,
    u16* __restrict__ wqk, u16* __restrict__ wv, u16* __restrict__ wo)
{
    const int tid = threadIdx.x;
    if (blockIdx.z == 16) {
        const int bid = blockIdx.y * 64 + blockIdx.x;   // 0..511
        const int sel = bid >> 7;
        const int sub = bid & 127;
        const float* s = sel == 0 ? Wq : sel == 1 ? Wk : sel == 2 ? Wv : Wo;
        u16* d = sel == 0 ? wqk : sel == 1 ? (wqk + 131072) : sel == 2 ? wv : wo;
        int i = (sub * 256 + tid) * 4;
        float4 v = *(const float4*)(s + i);
        u16x4 u = {f2bf(v.x), f2bf(v.y), f2bf(v.z), f2bf(v.w)};
        *(u16x4*)(d + i) = u;
        return;
    }
    __shared__ float Tx[64 * 65];
    const int b = blockIdx.z, c0 = blockIdx.y * 64, n0 = blockIdx.x * 64;
    const float* xb = x + (size_t)b * 512 * 4096;
    #pragma unroll
    for (int r = 0; r < 4; ++r) {
        int crow = (tid >> 4) + r * 16;
        int ncol = (tid & 15) * 4;
        float4 v = *(const float4*)(xb + (size_t)(c0 + crow) * 4096 + n0 + ncol);
        Tx[(ncol + 0) * 65 + crow] = v.x;
        Tx[(ncol + 1) * 65 + crow] = v.y;
        Tx[(ncol + 2) * 65 + crow] = v.z;
        Tx[(ncol + 3) * 65 + crow] = v.w;
    }
    __syncthreads();
    u16* ob = xT + (size_t)b * 4096 * 512;
    #pragma unroll
    for (int cc = 0; cc < 2; ++cc) {
        int id = cc * 256 + tid;
        int nrow = id >> 3;
        int cch = (id & 7) * 8;
        u16x8 u;
        #pragma unroll
        for (int j = 0; j < 8; ++j) u[j] = f2bf(Tx[nrow * 65 + cch + j]);
        *(u16x8*)(ob + (size_t)(n0 + nrow) * 512 + c0 + cch) = u;
    }
}

// ---------------------------------------------------------------------------
// K1: merged q/k/v. grid (16, 3, 16), 512 threads.
// y<2:  q,k = wqk . xT^T + bias  (m0 = y*256, n0 = x*256)
// y==2: vT[n][d] = xT[n][:] . Wv[d][:] + bv[d]  (m0 = x*256 over spatial)
// ---------------------------------------------------------------------------
__global__ __launch_bounds__(512, 2) void k1_qkv(
    const u16* __restrict__ wqk, const u16* __restrict__ wv,
    const float* __restrict__ bq, const float* __restrict__ bk, const float* __restrict__ bv,
    const u16* __restrict__ xT, u16* __restrict__ q, u16* __restrict__ kmat,
    u16* __restrict__ vT)
{
    __shared__ u16 sm[65536];
    const int b = blockIdx.z;
    const int y = blockIdx.y;
    const u16* xb = xT + (size_t)b * 4096 * 512;

    const int tid = threadIdx.x;
    const int l = tid & 63, w = tid >> 6;
    const int p = l & 15, g = l >> 4;
    const int wm = (w >> 2) * 128, wn = (w & 3) * 64;

    f32x4 acc[8][4] = {};

    if (y < 2) {
        const int m0 = y * 256;
        const int n0 = blockIdx.x * 256;
        gemm256<16>(wqk, 512, m0, 1, xb, 512, n0, sm, acc);

        const float* bias = (y == 0) ? bq : bk;
        u16* outp = ((y == 0) ? q : kmat) + ((size_t)b << 20);
        #pragma unroll
        for (int mf = 0; mf < 8; ++mf)
            #pragma unroll
            for (int nf = 0; nf < 4; ++nf) {
                int n = n0 + wn + nf * 16 + p;
                #pragma unroll
                for (int r = 0; r < 4; ++r) {
                    int mloc = wm + mf * 16 + g * 4 + r;
                    outp[(size_t)mloc * 4096 + n] = f2bf(acc[mf][nf][r] + bias[mloc]);
                }
            }
    } else {
        const int m0 = blockIdx.x * 256;
        gemm256<16>(xb, 512, m0, 1, wv, 512, 0, sm, acc);

        u16* outp = vT + ((size_t)b << 20);
        #pragma unroll
        for (int nf = 0; nf < 4; ++nf) {
            int d = wn + nf * 16 + p;
            float bvv = bv[d];
            #pragma unroll
            for (int mf = 0; mf < 8; ++mf) {
                #pragma unroll
                for (int r = 0; r < 4; ++r) {
                    int row = m0 + wm + mf * 16 + g * 4 + r;
                    outp[(size_t)row * 256 + d] = f2bf(acc[mf][nf][r] + bvv);
                }
            }
        }
    }
}

// ---------------------------------------------------------------------------
// K2: score partials, split-K=8. grid (8=split, 1, 16=b), 512 threads.
// K-slice = split*512 (pointer offset), NT=16.
// ---------------------------------------------------------------------------
__global__ __launch_bounds__(512, 2) void k2_scores(
    const u16* __restrict__ q, const u16* __restrict__ kmat, float* __restrict__ spart)
{
    __shared__ u16 sm[65536];
    const int b = blockIdx.z;
    const int split = blockIdx.x;
    const u16* A = q    + ((size_t)b << 20) + split * 512;
    const u16* B = kmat + ((size_t)b << 20) + split * 512;

    f32x4 acc[8][4] = {};
    gemm256<16>(A, 4096, 0, 1, B, 4096, 0, sm, acc);

    const int tid = threadIdx.x;
    const int l = tid & 63, w = tid >> 6;
    const int p = l & 15, g = l >> 4;
    const int wm = (w >> 2) * 128, wn = (w & 3) * 64;

    float* sp = spart + ((size_t)split * 16 + b) * 65536;
    #pragma unroll
    for (int mf = 0; mf < 8; ++mf)
        #pragma unroll
        for (int nf = 0; nf < 4; ++nf) {
            int n = wn + nf * 16 + p;
            #pragma unroll
            for (int r = 0; r < 4; ++r) {
                int m = wm + mf * 16 + g * 4 + r;
                sp[(size_t)m * 256 + n] = acc[mf][nf][r] * 0.015625f;
            }
        }
}

// ---------------------------------------------------------------------------
// K3: reduce 8 split partials + softmax over d -> bf16 attn
// ---------------------------------------------------------------------------
__global__ __launch_bounds__(256) void k3_softmax(
    const float* __restrict__ sp, u16* __restrict__ attn)
{
    const int row = blockIdx.x;
    const int tid = threadIdx.x;
    const size_t STRIDE = (size_t)16 * 65536;
    const size_t base = (size_t)row * 256 + tid;

    float s = 0.f;
    #pragma unroll
    for (int i = 0; i < 8; ++i) s += sp[base + i * STRIDE];

    __shared__ float red[4];
    float m = s;
    #pragma unroll
    for (int off = 32; off >= 1; off >>= 1) m = fmaxf(m, __shfl_xor(m, off));
    if ((tid & 63) == 0) red[tid >> 6] = m;
    __syncthreads();
    m = fmaxf(fmaxf(red[0], red[1]), fmaxf(red[2], red[3]));

    float e = expf(s - m);
    float t = e;
    #pragma unroll
    for (int off = 32; off >= 1; off >>= 1) t += __shfl_xor(t, off);
    __syncthreads();
    if ((tid & 63) == 0) red[tid >> 6] = t;
    __syncthreads();
    t = red[0] + red[1] + red[2] + red[3];

    attn[base] = f2bf(e / t);
}

// ---------------------------------------------------------------------------
// K4: outT3[b][sh][co][nh] = sum_d attn[b][co][d] * vT[b][16nh+sh][d]
// Per (b,sh): M=256 (nh via rstride-16 A rows), N=256 (co), K=256 (d), NT=8.
// grid (16=sh, 1, 16=b), 512 threads.
// ---------------------------------------------------------------------------
__global__ __launch_bounds__(512, 2) void k4_pv(
    const u16* __restrict__ attn, const u16* __restrict__ vT, u16* __restrict__ outT3)
{
    __shared__ u16 sm[65536];
    const int b  = blockIdx.z;
    const int sh = blockIdx.x;
    const u16* A = vT   + ((size_t)b << 20);   // rows 16m+sh
    const u16* B = attn + ((size_t)b << 16);

    f32x4 acc[8][4] = {};
    gemm256<8>(A, 256, sh, 16, B, 256, 0, sm, acc);

    const int tid = threadIdx.x;
    const int l = tid & 63, w = tid >> 6;
    const int p = l & 15, g = l >> 4;
    const int wm = (w >> 2) * 128, wn = (w & 3) * 64;

    u16* outp = outT3 + (((size_t)b * 16 + sh) << 16);
    #pragma unroll
    for (int mf = 0; mf < 8; ++mf)
        #pragma unroll
        for (int nf = 0; nf < 4; ++nf) {
            int co  = wn + nf * 16 + p;
            int nh0 = wm + mf * 16 + g * 4;
            u16x4 u = {f2bf(acc[mf][nf][0]), f2bf(acc[mf][nf][1]),
                       f2bf(acc[mf][nf][2]), f2bf(acc[mf][nf][3])};
            *(u16x4*)(outp + (size_t)co * 256 + nh0) = u;
        }
}

// ---------------------------------------------------------------------------
// K5: final[b][c][sh*256+slo] = sum_nh Wo[c][nh] * outT3[b][sh][slo][nh] + bo[c]
// Per (b,sh): M=512 (c), N=256 (slo), K=256 (nh), NT=8. grid (1, 2, 256).
// ---------------------------------------------------------------------------
__global__ __launch_bounds__(512, 2) void k5_final(
    const u16* __restrict__ wo, const float* __restrict__ bo,
    const u16* __restrict__ outT3, float* __restrict__ out)
{
    __shared__ u16 sm[65536];
    const int bz = blockIdx.z;               // b*16 + sh
    const int b  = bz >> 4, sh = bz & 15;
    const int m0 = blockIdx.y * 256;
    const u16* B = outT3 + ((size_t)bz << 16);

    f32x4 acc[8][4] = {};
    gemm256<8>(wo, 256, m0, 1, B, 256, 0, sm, acc);

    const int tid = threadIdx.x;
    const int l = tid & 63, w = tid >> 6;
    const int p = l & 15, g = l >> 4;
    const int wm = (w >> 2) * 128, wn = (w & 3) * 64;

    float* ob = out + (size_t)b * 2097152 + (size_t)sh * 256;
    #pragma unroll
    for (int mf = 0; mf < 8; ++mf)
        #pragma unroll
        for (int nf = 0; nf < 4; ++nf) {
            int slo = wn + nf * 16 + p;
            #pragma unroll
            for (int r = 0; r < 4; ++r) {
                int m = m0 + wm + mf * 16 + g * 4 + r;
                ob[(size_t)m * 4096 + slo] = acc[mf][nf][r] + bo[m];
            }
        }
}

// ---------------------------------------------------------------------------
extern "C" void kernel_launch(void* const* d_in, const int* in_sizes, int n_in,
                              void* d_out, int out_size, void* d_ws, size_t ws_size,
                              hipStream_t stream) {
    (void)in_sizes; (void)n_in; (void)out_size; (void)ws_size;
    const float* x  = (const float*)d_in[0];
    const float* Wq = (const float*)d_in[1];
    const float* bq = (const float*)d_in[2];
    const float* Wk = (const float*)d_in[3];
    const float* bk = (const float*)d_in[4];
    const float* Wv = (const float*)d_in[5];
    const float* bv = (const float*)d_in[6];
    const float* Wo = (const float*)d_in[7];
    const float* bo = (const float*)d_in[8];
    float* out = (float*)d_out;

    char* ws = (char*)d_ws;
    u16* xT   = (u16*)(ws + 0);             // 67.1MB, dead after k1
    u16* q    = (u16*)(ws + 67108864);      // 33.5MB, dead after k2
    u16* kmat = (u16*)(ws + 100663296);     // 33.5MB, dead after k2
    u16* vT   = (u16*)(ws + 134217728);     // 33.5MB, dead after k4
    float* spart = (float*)(ws + 0);        // 33.5MB f32 (8 splits), aliases xT
    u16* attn    = (u16*)(ws + 67108864);   // 2MB, aliases q
    u16* outT3   = (u16*)(ws + 100663296);  // 33.5MB, aliases kmat
    u16* wqk  = (u16*)(ws + 167772160);     // 512KB [512][512] (q rows then k rows)
    u16* wv   = (u16*)(ws + 168296448);     // 256KB [256][512]
    u16* wo   = (u16*)(ws + 168558592);     // 256KB [512][256]

    k0_prep   <<<dim3(64, 8, 17), dim3(256), 0, stream>>>(x, xT, Wq, Wk, Wv, Wo, wqk, wv, wo);
    k1_qkv    <<<dim3(16, 3, 16), dim3(512), 0, stream>>>(wqk, wv, bq, bk, bv, xT, q, kmat, vT);
    k2_scores <<<dim3(8, 1, 16),  dim3(512), 0, stream>>>(q, kmat, spart);
    k3_softmax<<<dim3(4096),      dim3(256), 0, stream>>>(spart, attn);
    k4_pv     <<<dim3(16, 1, 16), dim3(512), 0, stream>>>(attn, vT, outT3);
    k5_final  <<<dim3(1, 2, 256), dim3(512), 0, stream>>>(wo, bo, outT3, out);
}